// Round 10
// baseline (49.669 us; speedup 1.0000x reference)
//
#include <hip/hip_runtime.h>

// Problem constants (match reference)
#define BQ 32
#define TT 20000
#define NN 200
#define S3 600              // 3*N
#define JT 20               // j's per repack tile (60 floats = 240B runs, 16B-aligned)
#define NTILE (NN / JT)     // 10
#define SLOTS (JT * 9)      // 180
#define RELEMS ((size_t)NN * NN * 9 * BQ)   // 11,520,000 elements; fp16 -> 23.04 MB

typedef float    f32x4 __attribute__((ext_vector_type(4)));
typedef _Float16 f16x8 __attribute__((ext_vector_type(8)));   // 16B
typedef _Float16 f16x4 __attribute__((ext_vector_type(4)));   // 8B

// ---------------------------------------------------------------------------
// Kernel 1: repack H[b][3i+p][3j+q] -> R_f16[((i*N+j)*9 + p*3+q)*32 + b]
// (identical to the 32.5us R6 version)
// ---------------------------------------------------------------------------
__global__ __launch_bounds__(256) void repack_kernel(
    const float* __restrict__ H, _Float16* __restrict__ R)
{
    __shared__ float lds[SLOTS * 33];
    const int i   = blockIdx.x / NTILE;
    const int jt  = blockIdx.x % NTILE;
    const int c0  = 3 * JT * jt;
    const int tid = threadIdx.x;

    const int NE4 = BQ * 3 * 15;        // 1440 float4 per block
    for (int e = tid; e < NE4; e += 256) {
        int b   = e / 45;
        int rem = e - b * 45;
        int p   = rem / 15;
        int c4  = rem - p * 15;
        const float4 v = *reinterpret_cast<const float4*>(
            H + (size_t)b * (S3 * S3) + (size_t)(3 * i + p) * S3 + c0 + 4 * c4);
        const float vv[4] = {v.x, v.y, v.z, v.w};
#pragma unroll
        for (int x = 0; x < 4; ++x) {
            int c  = 4 * c4 + x;
            int jl = c / 3, q = c - 3 * jl;
            lds[(jl * 9 + p * 3 + q) * 33 + b] = vv[x];
        }
    }
    __syncthreads();

    f16x8* dst8 = reinterpret_cast<f16x8*>(R + (size_t)(i * NN + JT * jt) * 9 * BQ);
    const int NW8 = SLOTS * BQ / 8;     // 720
    for (int w = tid; w < NW8; w += 256) {
        int slot = w >> 2;
        int bh   = (w & 3) * 8;
        f16x8 v;
#pragma unroll
        for (int x = 0; x < 8; ++x)
            v[x] = (_Float16)lds[slot * 33 + bh + x];
        dst8[w] = v;
    }
}

// ---------------------------------------------------------------------------
// Shared compute
// ---------------------------------------------------------------------------
__device__ __forceinline__ void compute_errs(
    const float Mij[9], const float Mjk[9], const float Mki[9], float res[8])
{
    float N1[2][9];
#pragma unroll
    for (int p = 0; p < 3; ++p) {
#pragma unroll
        for (int r = 0; r < 3; ++r) {
            float c = Mij[p*3+0] * Mjk[0*3+r] + Mij[p*3+1] * Mjk[1*3+r];
            float d = Mij[p*3+2] * Mjk[2*3+r];
            N1[0][p*3+r] = c + d;
            N1[1][p*3+r] = c - d;
        }
    }
    float err[2][2];
#pragma unroll
    for (int u = 0; u < 2; ++u) {
        float T2p[9], T2m[9];
#pragma unroll
        for (int p = 0; p < 3; ++p) {
#pragma unroll
            for (int s = 0; s < 3; ++s) {
                float c = N1[u][p*3+0] * Mki[0*3+s] + N1[u][p*3+1] * Mki[1*3+s];
                float d = N1[u][p*3+2] * Mki[2*3+s];
                T2p[p*3+s] = c + d;
                T2m[p*3+s] = c - d;
            }
        }
#pragma unroll
        for (int v = 0; v < 2; ++v) {
            const float* T2 = (v == 0) ? T2p : T2m;
            float ss = 0.0f;
#pragma unroll
            for (int e = 0; e < 9; ++e) ss += T2[e] * T2[e];
            float diag = T2[0] + T2[4] + (((u ^ v) & 1) ? -T2[8] : T2[8]);
            float e2 = ss - 2.0f * diag + 3.0f;
            err[u][v] = sqrtf(fmaxf(e2, 0.0f));
        }
    }
#pragma unroll
    for (int m = 0; m < 8; ++m) {
        int a = (m >> 2) & 1, bb = (m >> 1) & 1, c = m & 1;
        res[m] = err[a ^ bb][bb ^ c];
    }
}

// ---------------------------------------------------------------------------
// Kernel 2a (R6's gather): 8 lanes/t, f16x4 loads, 4 batches/thread.
// ---------------------------------------------------------------------------
__global__ __launch_bounds__(256, 2) void gather4_kernel(
    const _Float16* __restrict__ R, const int* __restrict__ trip,
    float* __restrict__ out)
{
    int g  = blockIdx.x * 256 + threadIdx.x;   // 160000 threads exactly
    int bg = g & 7;
    int t  = g >> 3;

    int i = trip[3 * t + 0];
    int j = trip[3 * t + 1];
    int k = trip[3 * t + 2];

    const f16x4* __restrict__ Rij = reinterpret_cast<const f16x4*>(R) + (size_t)(i * NN + j) * 72 + bg;
    const f16x4* __restrict__ Rjk = reinterpret_cast<const f16x4*>(R) + (size_t)(j * NN + k) * 72 + bg;
    const f16x4* __restrict__ Rki = reinterpret_cast<const f16x4*>(R) + (size_t)(k * NN + i) * 72 + bg;

    f16x4 Aij[9], Ajk[9], Aki[9];
#pragma unroll
    for (int pq = 0; pq < 9; ++pq) {
        Aij[pq] = Rij[pq * 8];
        Ajk[pq] = Rjk[pq * 8];
        Aki[pq] = Rki[pq * 8];
    }

#pragma unroll
    for (int u = 0; u < 4; ++u) {
        float Mij[9], Mjk[9], Mki[9];
#pragma unroll
        for (int pq = 0; pq < 9; ++pq) {
            Mij[pq] = (float)Aij[pq][u];
            Mjk[pq] = (float)Ajk[pq][u];
            Mki[pq] = (float)Aki[pq][u];
        }
        float res[8];
        compute_errs(Mij, Mjk, Mki, res);

        int b = 4 * bg + u;
        f32x4* o4 = reinterpret_cast<f32x4*>(out + ((size_t)b * TT + t) * 8);
        f32x4 lo, hi;
        lo.x = res[0]; lo.y = res[1]; lo.z = res[2]; lo.w = res[3];
        hi.x = res[4]; hi.y = res[5]; hi.z = res[6]; hi.w = res[7];
        __builtin_nontemporal_store(lo, o4);
        __builtin_nontemporal_store(hi, o4 + 1);
    }
}

// ---------------------------------------------------------------------------
// Kernel 2c (probe): 4 lanes/t, f16x8 16B loads, 8 batches/thread.
// Requests: 27 per thread x 80K threads = 2.16M (half of gather4).
// Writes the SAME values as gather4 (idempotent; self-validating).
// ---------------------------------------------------------------------------
__global__ __launch_bounds__(256, 2) void gather8_kernel(
    const _Float16* __restrict__ R, const int* __restrict__ trip,
    float* __restrict__ out)
{
    int g  = blockIdx.x * 256 + threadIdx.x;
    int bg = g & 3;
    int t  = g >> 2;
    if (t >= TT) return;

    int i = trip[3 * t + 0];
    int j = trip[3 * t + 1];
    int k = trip[3 * t + 2];

    // f16x8 index: pair*36 + pq*4 + bg   (288 halfs per pair = 36 f16x8)
    const f16x8* __restrict__ Rij = reinterpret_cast<const f16x8*>(R) + (size_t)(i * NN + j) * 36 + bg;
    const f16x8* __restrict__ Rjk = reinterpret_cast<const f16x8*>(R) + (size_t)(j * NN + k) * 36 + bg;
    const f16x8* __restrict__ Rki = reinterpret_cast<const f16x8*>(R) + (size_t)(k * NN + i) * 36 + bg;

    f16x8 Aij[9], Ajk[9], Aki[9];
#pragma unroll
    for (int pq = 0; pq < 9; ++pq) {
        Aij[pq] = Rij[pq * 4];
        Ajk[pq] = Rjk[pq * 4];
        Aki[pq] = Rki[pq * 4];
    }

#pragma unroll
    for (int u = 0; u < 8; ++u) {        // compile-time u after unroll
        float Mij[9], Mjk[9], Mki[9];
#pragma unroll
        for (int pq = 0; pq < 9; ++pq) {
            Mij[pq] = (float)Aij[pq][u];
            Mjk[pq] = (float)Ajk[pq][u];
            Mki[pq] = (float)Aki[pq][u];
        }
        float res[8];
        compute_errs(Mij, Mjk, Mki, res);

        int b = 8 * bg + u;
        f32x4* o4 = reinterpret_cast<f32x4*>(out + ((size_t)b * TT + t) * 8);
        f32x4 lo, hi;
        lo.x = res[0]; lo.y = res[1]; lo.z = res[2]; lo.w = res[3];
        hi.x = res[4]; hi.y = res[5]; hi.z = res[6]; hi.w = res[7];
        __builtin_nontemporal_store(lo, o4);
        __builtin_nontemporal_store(hi, o4 + 1);
    }
}

// ---------------------------------------------------------------------------
// Fallback (direct kernel) in case ws is too small for R.
// ---------------------------------------------------------------------------
__global__ __launch_bounds__(256) void jcfg_err_direct(
    const float* __restrict__ H,
    const int*   __restrict__ trip,
    float*       __restrict__ out)
{
    int idx = blockIdx.x * blockDim.x + threadIdx.x;
    if (idx >= BQ * TT) return;
    int b = idx / TT;
    int t = idx - b * TT;

    int i = trip[3 * t + 0];
    int j = trip[3 * t + 1];
    int k = trip[3 * t + 2];

    const float* __restrict__ Hb = H + (size_t)b * (S3 * S3);

    float Mij[9], Mjk[9], Mki[9];
    const int ri = 3 * i, rj = 3 * j, rk = 3 * k;
#pragma unroll
    for (int p = 0; p < 3; ++p) {
        __builtin_memcpy(&Mij[3*p], Hb + (size_t)(ri + p) * S3 + rj, 12);
        __builtin_memcpy(&Mjk[3*p], Hb + (size_t)(rj + p) * S3 + rk, 12);
        __builtin_memcpy(&Mki[3*p], Hb + (size_t)(rk + p) * S3 + ri, 12);
    }

    float res[8];
    compute_errs(Mij, Mjk, Mki, res);

    float* o = out + (size_t)idx * 8;
    *reinterpret_cast<float4*>(o)     = make_float4(res[0], res[1], res[2], res[3]);
    *reinterpret_cast<float4*>(o + 4) = make_float4(res[4], res[5], res[6], res[7]);
}

extern "C" void kernel_launch(void* const* d_in, const int* in_sizes, int n_in,
                              void* d_out, int out_size, void* d_ws, size_t ws_size,
                              hipStream_t stream)
{
    const float* H    = (const float*)d_in[0];
    const int*   trip = (const int*)d_in[1];
    float*       out  = (float*)d_out;

    if (ws_size >= RELEMS * sizeof(_Float16)) {
        _Float16* R = (_Float16*)d_ws;
        repack_kernel<<<NN * NTILE, 256, 0, stream>>>(H, R);                // 2000 blocks
        // MEASUREMENT: dur(this) - dur(R6) == gather8 duration exactly.
        gather4_kernel<<<(TT * 8) / 256, 256, 0, stream>>>(R, trip, out);   // 625 blocks
        gather8_kernel<<<(TT * 4 + 255) / 256, 256, 0, stream>>>(R, trip, out); // 313 blocks
    } else {
        const int total = BQ * TT;
        jcfg_err_direct<<<(total + 255) / 256, 256, 0, stream>>>(H, trip, out);
    }
}

// Round 11
// 40.974 us; speedup vs baseline: 1.2122x; 1.2122x over previous
//
#include <hip/hip_runtime.h>

// Problem constants (match reference)
#define BQ 32
#define TT 20000
#define NN 200
#define S3 600              // 3*N
#define JT 20               // j's per repack tile (60 floats = 240B runs, 16B-aligned)
#define NTILE (NN / JT)     // 10
#define SLOTS (JT * 9)      // 180
#define RELEMS ((size_t)NN * NN * 9 * BQ)   // 11,520,000 elements; fp16 -> 23.04 MB

typedef float    f32x4 __attribute__((ext_vector_type(4)));
typedef _Float16 f16x8 __attribute__((ext_vector_type(8)));   // 16B
typedef _Float16 f16x4 __attribute__((ext_vector_type(4)));   // 8B

// ---------------------------------------------------------------------------
// Kernel 1: repack H[b][3i+p][3j+q] -> R_f16[((i*N+j)*9 + p*3+q)*32 + b]
// NT loads (H read once; keep out of L2) and NT stores (R write-through;
// avoid 23MB dirty-L2 flush stalling the dependent gather).
// ---------------------------------------------------------------------------
__global__ __launch_bounds__(256) void repack_kernel(
    const float* __restrict__ H, _Float16* __restrict__ R)
{
    __shared__ float lds[SLOTS * 33];   // *33 pad: conflict-free both phases
    const int i   = blockIdx.x / NTILE;
    const int jt  = blockIdx.x % NTILE;
    const int c0  = 3 * JT * jt;
    const int tid = threadIdx.x;

    const int NE4 = BQ * 3 * 15;        // 1440 float4 per block
    for (int e = tid; e < NE4; e += 256) {
        int b   = e / 45;
        int rem = e - b * 45;
        int p   = rem / 15;
        int c4  = rem - p * 15;
        const f32x4 v = __builtin_nontemporal_load(
            reinterpret_cast<const f32x4*>(
                H + (size_t)b * (S3 * S3) + (size_t)(3 * i + p) * S3 + c0 + 4 * c4));
#pragma unroll
        for (int x = 0; x < 4; ++x) {
            int c  = 4 * c4 + x;
            int jl = c / 3, q = c - 3 * jl;
            lds[(jl * 9 + p * 3 + q) * 33 + b] = v[x];
        }
    }
    __syncthreads();

    f16x8* dst8 = reinterpret_cast<f16x8*>(R + (size_t)(i * NN + JT * jt) * 9 * BQ);
    const int NW8 = SLOTS * BQ / 8;     // 720
    for (int w = tid; w < NW8; w += 256) {
        int slot = w >> 2;
        int bh   = (w & 3) * 8;
        f16x8 v;
#pragma unroll
        for (int x = 0; x < 8; ++x)
            v[x] = (_Float16)lds[slot * 33 + bh + x];
        __builtin_nontemporal_store(*reinterpret_cast<const f32x4*>(&v),
                                    reinterpret_cast<f32x4*>(dst8 + w));
    }
}

// ---------------------------------------------------------------------------
// Shared compute: four distinct products T2[u][v] = Mij * S^u * Mjk * S^v * Mki
// (S = diag(1,1,-1)); all 8 Frobenius errors derived from them.
// ---------------------------------------------------------------------------
__device__ __forceinline__ void compute_errs(
    const float Mij[9], const float Mjk[9], const float Mki[9], float res[8])
{
    float N1[2][9];
#pragma unroll
    for (int p = 0; p < 3; ++p) {
#pragma unroll
        for (int r = 0; r < 3; ++r) {
            float c = Mij[p*3+0] * Mjk[0*3+r] + Mij[p*3+1] * Mjk[1*3+r];
            float d = Mij[p*3+2] * Mjk[2*3+r];
            N1[0][p*3+r] = c + d;
            N1[1][p*3+r] = c - d;
        }
    }
    float err[2][2];
#pragma unroll
    for (int u = 0; u < 2; ++u) {
        float T2p[9], T2m[9];
#pragma unroll
        for (int p = 0; p < 3; ++p) {
#pragma unroll
            for (int s = 0; s < 3; ++s) {
                float c = N1[u][p*3+0] * Mki[0*3+s] + N1[u][p*3+1] * Mki[1*3+s];
                float d = N1[u][p*3+2] * Mki[2*3+s];
                T2p[p*3+s] = c + d;
                T2m[p*3+s] = c - d;
            }
        }
#pragma unroll
        for (int v = 0; v < 2; ++v) {
            const float* T2 = (v == 0) ? T2p : T2m;
            float ss = 0.0f;
#pragma unroll
            for (int e = 0; e < 9; ++e) ss += T2[e] * T2[e];
            float diag = T2[0] + T2[4] + (((u ^ v) & 1) ? -T2[8] : T2[8]);
            float e2 = ss - 2.0f * diag + 3.0f;
            err[u][v] = sqrtf(fmaxf(e2, 0.0f));
        }
    }
#pragma unroll
    for (int m = 0; m < 8; ++m) {
        int a = (m >> 2) & 1, bb = (m >> 1) & 1, c = m & 1;
        res[m] = err[a ^ bb][bb ^ c];
    }
}

// ---------------------------------------------------------------------------
// Kernel 2: gather from R. 8 lanes/t, f16x4 loads, 4 batches/thread.
// (R10 measurement: this thread-count/request-count point is the sweet spot.)
// ---------------------------------------------------------------------------
__global__ __launch_bounds__(256, 2) void gather4_kernel(
    const _Float16* __restrict__ R, const int* __restrict__ trip,
    float* __restrict__ out)
{
    int g  = blockIdx.x * 256 + threadIdx.x;   // 160000 threads exactly
    int bg = g & 7;
    int t  = g >> 3;

    int i = trip[3 * t + 0];
    int j = trip[3 * t + 1];
    int k = trip[3 * t + 2];

    const f16x4* __restrict__ Rij = reinterpret_cast<const f16x4*>(R) + (size_t)(i * NN + j) * 72 + bg;
    const f16x4* __restrict__ Rjk = reinterpret_cast<const f16x4*>(R) + (size_t)(j * NN + k) * 72 + bg;
    const f16x4* __restrict__ Rki = reinterpret_cast<const f16x4*>(R) + (size_t)(k * NN + i) * 72 + bg;

    f16x4 Aij[9], Ajk[9], Aki[9];
#pragma unroll
    for (int pq = 0; pq < 9; ++pq) {
        Aij[pq] = Rij[pq * 8];
        Ajk[pq] = Rjk[pq * 8];
        Aki[pq] = Rki[pq * 8];
    }

#pragma unroll
    for (int u = 0; u < 4; ++u) {
        float Mij[9], Mjk[9], Mki[9];
#pragma unroll
        for (int pq = 0; pq < 9; ++pq) {
            Mij[pq] = (float)Aij[pq][u];
            Mjk[pq] = (float)Ajk[pq][u];
            Mki[pq] = (float)Aki[pq][u];
        }
        float res[8];
        compute_errs(Mij, Mjk, Mki, res);

        int b = 4 * bg + u;
        f32x4* o4 = reinterpret_cast<f32x4*>(out + ((size_t)b * TT + t) * 8);
        f32x4 lo, hi;
        lo.x = res[0]; lo.y = res[1]; lo.z = res[2]; lo.w = res[3];
        hi.x = res[4]; hi.y = res[5]; hi.z = res[6]; hi.w = res[7];
        __builtin_nontemporal_store(lo, o4);
        __builtin_nontemporal_store(hi, o4 + 1);
    }
}

// ---------------------------------------------------------------------------
// Fallback (direct kernel) in case ws is too small for R.
// ---------------------------------------------------------------------------
__global__ __launch_bounds__(256) void jcfg_err_direct(
    const float* __restrict__ H,
    const int*   __restrict__ trip,
    float*       __restrict__ out)
{
    int idx = blockIdx.x * blockDim.x + threadIdx.x;
    if (idx >= BQ * TT) return;
    int b = idx / TT;
    int t = idx - b * TT;

    int i = trip[3 * t + 0];
    int j = trip[3 * t + 1];
    int k = trip[3 * t + 2];

    const float* __restrict__ Hb = H + (size_t)b * (S3 * S3);

    float Mij[9], Mjk[9], Mki[9];
    const int ri = 3 * i, rj = 3 * j, rk = 3 * k;
#pragma unroll
    for (int p = 0; p < 3; ++p) {
        __builtin_memcpy(&Mij[3*p], Hb + (size_t)(ri + p) * S3 + rj, 12);
        __builtin_memcpy(&Mjk[3*p], Hb + (size_t)(rj + p) * S3 + rk, 12);
        __builtin_memcpy(&Mki[3*p], Hb + (size_t)(rk + p) * S3 + ri, 12);
    }

    float res[8];
    compute_errs(Mij, Mjk, Mki, res);

    float* o = out + (size_t)idx * 8;
    *reinterpret_cast<float4*>(o)     = make_float4(res[0], res[1], res[2], res[3]);
    *reinterpret_cast<float4*>(o + 4) = make_float4(res[4], res[5], res[6], res[7]);
}

extern "C" void kernel_launch(void* const* d_in, const int* in_sizes, int n_in,
                              void* d_out, int out_size, void* d_ws, size_t ws_size,
                              hipStream_t stream)
{
    const float* H    = (const float*)d_in[0];
    const int*   trip = (const int*)d_in[1];
    float*       out  = (float*)d_out;

    if (ws_size >= RELEMS * sizeof(_Float16)) {
        _Float16* R = (_Float16*)d_ws;
        repack_kernel<<<NN * NTILE, 256, 0, stream>>>(H, R);               // 2000 blocks
        gather4_kernel<<<(TT * 8) / 256, 256, 0, stream>>>(R, trip, out);  // 625 blocks
    } else {
        const int total = BQ * TT;
        jcfg_err_direct<<<(total + 255) / 256, 256, 0, stream>>>(H, trip, out);
    }
}

// Round 12
// 29.389 us; speedup vs baseline: 1.6900x; 1.3942x over previous
//
#include <hip/hip_runtime.h>

// Problem constants (match reference)
#define BQ 32
#define TT 20000
#define NN 200
#define S3 600              // 3*N
#define BPERH 16            // batches per repack block (b-half)
#define LSTRIDE 1804        // lds halfs per batch slab (600*3 + 4 pad)
#define HALF_HALFS ((size_t)NN * NN * 9 * 16)   // 5,760,000 halfs = 11.52 MB per half-array
#define R_BYTES (2 * HALF_HALFS * sizeof(_Float16))   // 23.04 MB total

typedef float    f32x4 __attribute__((ext_vector_type(4)));
typedef _Float16 f16x8 __attribute__((ext_vector_type(8)));   // 16B
typedef _Float16 f16x4 __attribute__((ext_vector_type(4)));   // 8B

// ---------------------------------------------------------------------------
// Kernel 1: streaming repack.
// Block = (i, bh): reads rows 3i..3i+2 of 16 batches — 16 contiguous 7.2KB
// runs — into an fp16 LDS slab; writes one 57.6KB fully-contiguous chunk of
// R_bh[pair][pq][16] (b_local inner). Both global sides are streaming.
// ---------------------------------------------------------------------------
__global__ __launch_bounds__(512) void repack2_kernel(
    const float* __restrict__ H,
    _Float16* __restrict__ R0, _Float16* __restrict__ R1)
{
    __shared__ _Float16 lds16[BPERH * LSTRIDE];   // 57,728 B
    const int i  = blockIdx.x >> 1;
    const int bh = blockIdx.x & 1;
    const int tid = threadIdx.x;

    // Load: 7200 f32x4 = 16 bl x 3 p x 150 c4; contiguous 7.2KB per bl.
    for (int e = tid; e < BPERH * 3 * 150; e += 512) {
        int bl  = e / 450;
        int rem = e - bl * 450;
        int p   = rem / 150;
        int c4  = rem - p * 150;
        const f32x4 v = *reinterpret_cast<const f32x4*>(
            H + (size_t)(bh * BPERH + bl) * (S3 * S3)
              + (size_t)(3 * i + p) * S3 + 4 * c4);
        f16x4 hv;
#pragma unroll
        for (int x = 0; x < 4; ++x) hv[x] = (_Float16)v[x];
        *reinterpret_cast<f16x4*>(&lds16[bl * LSTRIDE + p * 600 + 4 * c4]) = hv;
    }
    __syncthreads();

    // Store: 3600 f16x8, fully contiguous. w = j*18 + pq*2 + h exactly matches
    // the output half-index ((j*9+pq)*16 + h*8)/8.
    _Float16* __restrict__ Rh = bh ? R1 : R0;
    f16x8* dst = reinterpret_cast<f16x8*>(Rh + (size_t)i * (NN * 9 * 16));
    for (int w = tid; w < 3600; w += 512) {
        int j  = w / 18;
        int r  = w - j * 18;
        int pq = r >> 1;
        int h  = r & 1;
        int p  = pq / 3, q = pq - 3 * p;
        f16x8 v;
#pragma unroll
        for (int x = 0; x < 8; ++x)
            v[x] = lds16[(h * 8 + x) * LSTRIDE + p * 600 + 3 * j + q];
        dst[w] = v;
    }
}

// ---------------------------------------------------------------------------
// Shared compute: four distinct products T2[u][v] = Mij * S^u * Mjk * S^v * Mki
// (S = diag(1,1,-1)); all 8 Frobenius errors derived from them.
// ---------------------------------------------------------------------------
__device__ __forceinline__ void compute_errs(
    const float Mij[9], const float Mjk[9], const float Mki[9], float res[8])
{
    float N1[2][9];
#pragma unroll
    for (int p = 0; p < 3; ++p) {
#pragma unroll
        for (int r = 0; r < 3; ++r) {
            float c = Mij[p*3+0] * Mjk[0*3+r] + Mij[p*3+1] * Mjk[1*3+r];
            float d = Mij[p*3+2] * Mjk[2*3+r];
            N1[0][p*3+r] = c + d;
            N1[1][p*3+r] = c - d;
        }
    }
    float err[2][2];
#pragma unroll
    for (int u = 0; u < 2; ++u) {
        float T2p[9], T2m[9];
#pragma unroll
        for (int p = 0; p < 3; ++p) {
#pragma unroll
            for (int s = 0; s < 3; ++s) {
                float c = N1[u][p*3+0] * Mki[0*3+s] + N1[u][p*3+1] * Mki[1*3+s];
                float d = N1[u][p*3+2] * Mki[2*3+s];
                T2p[p*3+s] = c + d;
                T2m[p*3+s] = c - d;
            }
        }
#pragma unroll
        for (int v = 0; v < 2; ++v) {
            const float* T2 = (v == 0) ? T2p : T2m;
            float ss = 0.0f;
#pragma unroll
            for (int e = 0; e < 9; ++e) ss += T2[e] * T2[e];
            float diag = T2[0] + T2[4] + (((u ^ v) & 1) ? -T2[8] : T2[8]);
            float e2 = ss - 2.0f * diag + 3.0f;
            err[u][v] = sqrtf(fmaxf(e2, 0.0f));
        }
    }
#pragma unroll
    for (int m = 0; m < 8; ++m) {
        int a = (m >> 2) & 1, bb = (m >> 1) & 1, c = m & 1;
        res[m] = err[a ^ bb][bb ^ c];
    }
}

// ---------------------------------------------------------------------------
// Kernel 2: gather. 8 lanes/t; lane bg picks half-array bg>>2 and f16x4 slot
// bg&3. Per (pair,pq): the 4 lanes of each half consume one full 32B run.
// 4 batches per thread (b = (bg>>2)*16 + (bg&3)*4 + u).
// ---------------------------------------------------------------------------
__global__ __launch_bounds__(256, 2) void gather4_kernel(
    const _Float16* __restrict__ R0, const _Float16* __restrict__ R1,
    const int* __restrict__ trip, float* __restrict__ out)
{
    int g  = blockIdx.x * 256 + threadIdx.x;   // 160000 threads exactly
    int bg = g & 7;
    int t  = g >> 3;

    int i = trip[3 * t + 0];
    int j = trip[3 * t + 1];
    int k = trip[3 * t + 2];

    const _Float16* __restrict__ Rs = (bg < 4) ? R0 : R1;
    const int bl4 = bg & 3;

    // f16x4 index: pair*36 + pq*4 + bl4   (144 halfs per pair per half-array)
    const f16x4* __restrict__ Pij = reinterpret_cast<const f16x4*>(Rs) + (size_t)(i * NN + j) * 36 + bl4;
    const f16x4* __restrict__ Pjk = reinterpret_cast<const f16x4*>(Rs) + (size_t)(j * NN + k) * 36 + bl4;
    const f16x4* __restrict__ Pki = reinterpret_cast<const f16x4*>(Rs) + (size_t)(k * NN + i) * 36 + bl4;

    f16x4 Aij[9], Ajk[9], Aki[9];
#pragma unroll
    for (int pq = 0; pq < 9; ++pq) {
        Aij[pq] = Pij[pq * 4];
        Ajk[pq] = Pjk[pq * 4];
        Aki[pq] = Pki[pq * 4];
    }

#pragma unroll
    for (int u = 0; u < 4; ++u) {
        float Mij[9], Mjk[9], Mki[9];
#pragma unroll
        for (int pq = 0; pq < 9; ++pq) {
            Mij[pq] = (float)Aij[pq][u];
            Mjk[pq] = (float)Ajk[pq][u];
            Mki[pq] = (float)Aki[pq][u];
        }
        float res[8];
        compute_errs(Mij, Mjk, Mki, res);

        int b = (bg >> 2) * 16 + bl4 * 4 + u;
        f32x4* o4 = reinterpret_cast<f32x4*>(out + ((size_t)b * TT + t) * 8);
        f32x4 lo, hi;
        lo.x = res[0]; lo.y = res[1]; lo.z = res[2]; lo.w = res[3];
        hi.x = res[4]; hi.y = res[5]; hi.z = res[6]; hi.w = res[7];
        __builtin_nontemporal_store(lo, o4);
        __builtin_nontemporal_store(hi, o4 + 1);
    }
}

// ---------------------------------------------------------------------------
// Fallback (direct kernel) in case ws is too small for R.
// ---------------------------------------------------------------------------
__global__ __launch_bounds__(256) void jcfg_err_direct(
    const float* __restrict__ H,
    const int*   __restrict__ trip,
    float*       __restrict__ out)
{
    int idx = blockIdx.x * blockDim.x + threadIdx.x;
    if (idx >= BQ * TT) return;
    int b = idx / TT;
    int t = idx - b * TT;

    int i = trip[3 * t + 0];
    int j = trip[3 * t + 1];
    int k = trip[3 * t + 2];

    const float* __restrict__ Hb = H + (size_t)b * (S3 * S3);

    float Mij[9], Mjk[9], Mki[9];
    const int ri = 3 * i, rj = 3 * j, rk = 3 * k;
#pragma unroll
    for (int p = 0; p < 3; ++p) {
        __builtin_memcpy(&Mij[3*p], Hb + (size_t)(ri + p) * S3 + rj, 12);
        __builtin_memcpy(&Mjk[3*p], Hb + (size_t)(rj + p) * S3 + rk, 12);
        __builtin_memcpy(&Mki[3*p], Hb + (size_t)(rk + p) * S3 + ri, 12);
    }

    float res[8];
    compute_errs(Mij, Mjk, Mki, res);

    float* o = out + (size_t)idx * 8;
    *reinterpret_cast<float4*>(o)     = make_float4(res[0], res[1], res[2], res[3]);
    *reinterpret_cast<float4*>(o + 4) = make_float4(res[4], res[5], res[6], res[7]);
}

extern "C" void kernel_launch(void* const* d_in, const int* in_sizes, int n_in,
                              void* d_out, int out_size, void* d_ws, size_t ws_size,
                              hipStream_t stream)
{
    const float* H    = (const float*)d_in[0];
    const int*   trip = (const int*)d_in[1];
    float*       out  = (float*)d_out;

    if (ws_size >= R_BYTES) {
        _Float16* R0 = (_Float16*)d_ws;
        _Float16* R1 = R0 + HALF_HALFS;
        repack2_kernel<<<NN * 2, 512, 0, stream>>>(H, R0, R1);                 // 400 blocks
        gather4_kernel<<<(TT * 8) / 256, 256, 0, stream>>>(R0, R1, trip, out); // 625 blocks
    } else {
        const int total = BQ * TT;
        jcfg_err_direct<<<(total + 255) / 256, 256, 0, stream>>>(H, trip, out);
    }
}